// Round 1
// baseline (1056.150 us; speedup 1.0000x reference)
//
#include <hip/hip_runtime.h>
#include <hip/hip_bf16.h>
#include <float.h>

#define GG    64
#define NPG   1024
#define EPG   8192      // edges per graph
#define NE    524288
#define FIN   128
#define HID   256
#define K1    512
#define K2    256
#define NN0   65536     // GG*NPG
#define NN1   32768     // GG*K1
#define NN2   16384     // GG*K2
#define EPSBN 1e-5f

__device__ __forceinline__ float gelu_exact(float v) {
    return 0.5f * v * (1.0f + erff(v * 0.7071067811865476f));
}

// ---------- small prep kernels ----------
__global__ __launch_bounds__(256) void k_w1cat(const float* __restrict__ Wrel,
        const float* __restrict__ Wroot, float* __restrict__ Wc) {
    const int i = blockIdx.x * 256 + threadIdx.x;       // 65536 = 256x256
    const int k = i >> 8, n = i & 255;
    Wc[i] = (k < FIN) ? Wrel[k * HID + n] : Wroot[(k - FIN) * HID + n];
}

__global__ __launch_bounds__(256) void k_w2cat(const float* __restrict__ Wrel,
        const float* __restrict__ Wroot, float* __restrict__ Wc) {
    const int i = blockIdx.x * 256 + threadIdx.x;       // 131072 = 512x256
    const int k = i >> 8, n = i & 255;
    Wc[i] = (k < HID) ? Wrel[k * HID + n] : Wroot[(k - HID) * HID + n];
}

__global__ __launch_bounds__(256) void k_q2norm(const float* __restrict__ p2,
        float* __restrict__ q2) {
    __shared__ float red[256];
    const int c = threadIdx.x;
    const float pv = p2[c];
    red[c] = pv * pv;
    __syncthreads();
    for (int s = 128; s > 0; s >>= 1) {
        if (c < s) red[c] += red[c + s];
        __syncthreads();
    }
    q2[c] = pv * rsqrtf(red[0]);
}

__global__ __launch_bounds__(256) void k_copy_x(const float* __restrict__ x,
        float* __restrict__ A1) {
    const int total = NN0 * (FIN / 4);                  // float4 count
    for (int i = blockIdx.x * 256 + threadIdx.x; i < total; i += gridDim.x * 256) {
        const int r = i >> 5, c4 = i & 31;
        reinterpret_cast<float4*>(A1)[(size_t)r * 64 + 32 + c4] =
            reinterpret_cast<const float4*>(x)[i];
    }
}

// ---------- aggregation (per-graph LDS accumulate) ----------
__global__ __launch_bounds__(256) void k_agg1(const float* __restrict__ x,
        const int* __restrict__ src, const int* __restrict__ dst,
        float* __restrict__ A1) {
    __shared__ float lds[NPG * 8];                      // 32 KiB
    const int g = blockIdx.x >> 4;                      // 16 chunks of 8 cols
    const int ch = blockIdx.x & 15;
    const int tid = threadIdx.x;
    for (int i = tid; i < NPG * 8; i += 256) lds[i] = 0.f;
    __syncthreads();
    const int f = tid & 7, sub = tid >> 3;
    const int ebase = g * EPG;
    const int c0 = ch * 8;
    for (int eb = sub; eb < EPG; eb += 32) {
        const int e = ebase + eb;
        const int s = src[e];
        const int d = dst[e] - (g << 10);
        const float v = x[(size_t)s * FIN + c0 + f];
        unsafeAtomicAdd(&lds[(d << 3) + f], v);
    }
    __syncthreads();
    for (int i = tid; i < NPG * 8; i += 256) {
        const int r = i >> 3, cc = i & 7;
        A1[(size_t)((g << 10) | r) * 256 + c0 + cc] = lds[i];
    }
}

__global__ __launch_bounds__(256) void k_agg2(const float* __restrict__ A2r,
        const int* __restrict__ ns, const int* __restrict__ nd,
        float* __restrict__ A2w) {
    __shared__ float lds[K1 * 16];                      // 32 KiB
    const int g = blockIdx.x >> 4;                      // 16 chunks of 16 cols
    const int ch = blockIdx.x & 15;
    const int tid = threadIdx.x;
    for (int i = tid; i < K1 * 16; i += 256) lds[i] = 0.f;
    __syncthreads();
    const int f = tid & 15, sub = tid >> 4;
    const int ebase = g * EPG;
    const int c0 = ch * 16;
    for (int eb = sub; eb < EPG; eb += 16) {
        const int e = ebase + eb;
        const int a = ns[e];
        if (a < 0) continue;
        const int b = nd[e] - (g << 9);
        const float v = A2r[(size_t)a * 512 + 256 + c0 + f];
        unsafeAtomicAdd(&lds[(b << 4) + f], v);
    }
    __syncthreads();
    for (int i = tid; i < K1 * 16; i += 256) {
        const int r = i >> 4, cc = i & 15;
        A2w[(size_t)((g << 9) | r) * 512 + c0 + cc] = lds[i];
    }
}

// ---------- fp32 SGEMM, 128x128 tile, optional gelu+BN-stats epilogue ----------
template<int EPI>   // 0: +bias; 1: +bias, gelu, column sum/sumsq stats
__global__ __launch_bounds__(256) void k_gemm128(
        const float* __restrict__ A, const float* __restrict__ B,
        const float* __restrict__ bias, float* __restrict__ C,
        float* __restrict__ stats, int M, int K, int N) {
    __shared__ float As[16][128];
    __shared__ float Bs[16][128];
    __shared__ float csum[128];
    __shared__ float csq[128];
    const int tid = threadIdx.x;
    const int tx = tid & 15, ty = tid >> 4;
    const int m0 = blockIdx.x * 128, n0 = blockIdx.y * 128;

    float acc[8][8];
#pragma unroll
    for (int i = 0; i < 8; ++i)
#pragma unroll
        for (int j = 0; j < 8; ++j) acc[i][j] = 0.f;

    const int ar = tid >> 2, akc = (tid & 3) << 2;
    const int bkr = tid >> 4, bnc = (tid & 15) << 3;

    for (int k0 = 0; k0 < K; k0 += 16) {
        const float4 a0 = *reinterpret_cast<const float4*>(A + (size_t)(m0 + ar) * K + k0 + akc);
        const float4 a1 = *reinterpret_cast<const float4*>(A + (size_t)(m0 + ar + 64) * K + k0 + akc);
        const float4 b0 = *reinterpret_cast<const float4*>(B + (size_t)(k0 + bkr) * N + n0 + bnc);
        const float4 b1 = *reinterpret_cast<const float4*>(B + (size_t)(k0 + bkr) * N + n0 + bnc + 4);
        __syncthreads();
        As[akc + 0][ar] = a0.x; As[akc + 1][ar] = a0.y; As[akc + 2][ar] = a0.z; As[akc + 3][ar] = a0.w;
        As[akc + 0][ar + 64] = a1.x; As[akc + 1][ar + 64] = a1.y; As[akc + 2][ar + 64] = a1.z; As[akc + 3][ar + 64] = a1.w;
        *reinterpret_cast<float4*>(&Bs[bkr][bnc]) = b0;
        *reinterpret_cast<float4*>(&Bs[bkr][bnc + 4]) = b1;
        __syncthreads();
#pragma unroll
        for (int k = 0; k < 16; ++k) {
            const float4 av0 = *reinterpret_cast<const float4*>(&As[k][ty << 2]);
            const float4 av1 = *reinterpret_cast<const float4*>(&As[k][64 + (ty << 2)]);
            const float4 bv0 = *reinterpret_cast<const float4*>(&Bs[k][tx << 2]);
            const float4 bv1 = *reinterpret_cast<const float4*>(&Bs[k][64 + (tx << 2)]);
            const float a[8] = {av0.x, av0.y, av0.z, av0.w, av1.x, av1.y, av1.z, av1.w};
            const float b[8] = {bv0.x, bv0.y, bv0.z, bv0.w, bv1.x, bv1.y, bv1.z, bv1.w};
#pragma unroll
            for (int i = 0; i < 8; ++i)
#pragma unroll
                for (int j = 0; j < 8; ++j) acc[i][j] = fmaf(a[i], b[j], acc[i][j]);
        }
    }

    if (EPI == 1) {
        if (tid < 128) { csum[tid] = 0.f; csq[tid] = 0.f; }
        __syncthreads();
    }

    const float4 bia0 = *reinterpret_cast<const float4*>(bias + n0 + (tx << 2));
    const float4 bia1 = *reinterpret_cast<const float4*>(bias + n0 + 64 + (tx << 2));
    const float bcol[8] = {bia0.x, bia0.y, bia0.z, bia0.w, bia1.x, bia1.y, bia1.z, bia1.w};
    float sArr[8] = {0, 0, 0, 0, 0, 0, 0, 0};
    float qArr[8] = {0, 0, 0, 0, 0, 0, 0, 0};

#pragma unroll
    for (int i = 0; i < 8; ++i) {
        const int row = m0 + ((i < 4) ? ((ty << 2) + i) : (64 + (ty << 2) + i - 4));
        float v[8];
#pragma unroll
        for (int j = 0; j < 8; ++j) {
            float t = acc[i][j] + bcol[j];
            if (EPI == 1) {
                t = gelu_exact(t);
                sArr[j] += t;
                qArr[j] += t * t;
            }
            v[j] = t;
        }
        *reinterpret_cast<float4*>(C + (size_t)row * N + n0 + (tx << 2)) =
            make_float4(v[0], v[1], v[2], v[3]);
        *reinterpret_cast<float4*>(C + (size_t)row * N + n0 + 64 + (tx << 2)) =
            make_float4(v[4], v[5], v[6], v[7]);
    }
    if (EPI == 1) {
#pragma unroll
        for (int j = 0; j < 8; ++j) {
            const int cl = (j < 4) ? ((tx << 2) + j) : (64 + (tx << 2) + j - 4);
            unsafeAtomicAdd(&csum[cl], sArr[j]);
            unsafeAtomicAdd(&csq[cl], qArr[j]);
        }
        __syncthreads();
        if (tid < 128) {
            unsafeAtomicAdd(&stats[n0 + tid], csum[tid]);
            unsafeAtomicAdd(&stats[HID + n0 + tid], csq[tid]);
        }
    }
}

// ---------- BN finalize / score fold ----------
__global__ __launch_bounds__(256) void k_finalize1(const float* __restrict__ stats,
        const float* __restrict__ g1, const float* __restrict__ bt1,
        const float* __restrict__ p1, float* __restrict__ scale,
        float* __restrict__ shift, float* __restrict__ q, float* __restrict__ r) {
    __shared__ float red[256];
    const int c = threadIdx.x;
    const float m = stats[c] * (1.f / NN0);
    const float v = stats[HID + c] * (1.f / NN0) - m * m;
    const float sc = g1[c] * rsqrtf(v + EPSBN);
    const float sh = bt1[c] - m * sc;
    scale[c] = sc;
    shift[c] = sh;
    const float pv = p1[c];
    red[c] = pv * pv;
    __syncthreads();
    for (int s = 128; s > 0; s >>= 1) {
        if (c < s) red[c] += red[c + s];
        __syncthreads();
    }
    const float inv = rsqrtf(red[0]);
    q[c] = sc * pv * inv;
    __syncthreads();
    red[c] = sh * pv * inv;
    __syncthreads();
    for (int s = 128; s > 0; s >>= 1) {
        if (c < s) red[c] += red[c + s];
        __syncthreads();
    }
    if (c == 0) r[0] = red[0];
}

__global__ __launch_bounds__(256) void k_finalize2(const float* __restrict__ stats,
        const float* __restrict__ g2, const float* __restrict__ bt2,
        float* __restrict__ scale, float* __restrict__ shift) {
    const int c = threadIdx.x;
    const float m = stats[c] * (1.f / NN1);
    const float v = stats[HID + c] * (1.f / NN1) - m * m;
    const float sc = g2[c] * rsqrtf(v + EPSBN);
    scale[c] = sc;
    shift[c] = bt2[c] - m * sc;
}

// ---------- scores: tanh(h . q + r), one wave per node ----------
__global__ __launch_bounds__(256) void k_score(const float* __restrict__ H,
        const float* __restrict__ q, const float* __restrict__ r,
        float* __restrict__ out) {
    const int node = blockIdx.x * 4 + (threadIdx.x >> 6);
    const int lane = threadIdx.x & 63;
    const float4 h = *reinterpret_cast<const float4*>(H + (size_t)node * HID + (lane << 2));
    const float4 qv = *reinterpret_cast<const float4*>(q + (lane << 2));
    float d = h.x * qv.x + h.y * qv.y + h.z * qv.z + h.w * qv.w;
#pragma unroll
    for (int off = 32; off > 0; off >>= 1) d += __shfl_xor(d, off);
    if (lane == 0) out[node] = tanhf(d + (r ? r[0] : 0.f));
}

// ---------- per-graph bitonic top-k ----------
template<int NN_, int KK_, int NT_>
__global__ __launch_bounds__(NT_) void k_topk(const float* __restrict__ scores,
        int* __restrict__ perm, float* __restrict__ vals, int* __restrict__ mapping) {
    __shared__ float s[NN_];
    __shared__ int id[NN_];
    const int g = blockIdx.x, tid = threadIdx.x;
    for (int i = tid; i < NN_; i += NT_) { s[i] = scores[g * NN_ + i]; id[i] = i; }
    __syncthreads();
    for (int k = 2; k <= NN_; k <<= 1) {
        for (int j = k >> 1; j > 0; j >>= 1) {
            for (int t = tid; t < NN_; t += NT_) {
                const int ixj = t ^ j;
                if (ixj > t) {
                    const bool desc = ((t & k) == 0);
                    const float s1 = s[t], s2 = s[ixj];
                    const int i1 = id[t], i2 = id[ixj];
                    const bool inOrder = (s1 > s2) || (s1 == s2 && i1 < i2);
                    if (inOrder != desc) { s[t] = s2; s[ixj] = s1; id[t] = i2; id[ixj] = i1; }
                }
            }
            __syncthreads();
        }
    }
    for (int i = tid; i < KK_; i += NT_) {
        const int oid = id[i];
        perm[g * KK_ + i] = g * NN_ + oid;
        vals[g * KK_ + i] = s[i];
        if (mapping) mapping[g * NN_ + oid] = g * KK_ + i;
    }
}

// ---------- pool1 apply: gather+BN+scale, write h1p, x1 readout, bn2 stats ----------
__global__ __launch_bounds__(256) void k_pool1(const float* __restrict__ HG,
        const int* __restrict__ perm, const float* __restrict__ vals,
        const float* __restrict__ scale1, const float* __restrict__ shift1,
        float* __restrict__ H1P, float* __restrict__ X1, float* __restrict__ stats2) {
    const int g = blockIdx.x, c = threadIdx.x;
    const float sc = scale1[c], sh = shift1[c];
    float mx = -FLT_MAX, sm = 0.f, sq = 0.f;
    for (int i = 0; i < K1; ++i) {
        const int idx = g * K1 + i;
        const int srow = perm[idx];
        const float val = vals[idx];
        const float hv = HG[(size_t)srow * HID + c];
        const float xn = (hv * sc + sh) * val;
        H1P[(size_t)idx * HID + c] = xn;
        mx = fmaxf(mx, xn);
        sm += xn;
        sq += xn * xn;
    }
    X1[g * 512 + c] = mx;
    X1[g * 512 + 256 + c] = sm * (1.f / K1);
    unsafeAtomicAdd(&stats2[c], sm);
    unsafeAtomicAdd(&stats2[HID + c], sq);
}

// ---------- h2in = gelu(bn2(h1p)) into A2 right half ----------
__global__ __launch_bounds__(256) void k_h2in(const float* __restrict__ H1P,
        const float* __restrict__ scale2, const float* __restrict__ shift2,
        float* __restrict__ A2) {
    const int total = NN1 * (HID / 4);
    for (int i = blockIdx.x * 256 + threadIdx.x; i < total; i += gridDim.x * 256) {
        const int r = i >> 6, c4 = i & 63;
        const float4 v = reinterpret_cast<const float4*>(H1P)[i];
        const float4 sc = reinterpret_cast<const float4*>(scale2)[c4];
        const float4 sh = reinterpret_cast<const float4*>(shift2)[c4];
        float4 o;
        o.x = gelu_exact(v.x * sc.x + sh.x);
        o.y = gelu_exact(v.y * sc.y + sh.y);
        o.z = gelu_exact(v.z * sc.z + sh.z);
        o.w = gelu_exact(v.w * sc.w + sh.w);
        reinterpret_cast<float4*>(A2)[(size_t)r * 128 + 64 + c4] = o;
    }
}

// ---------- edge remap through mapping ----------
__global__ __launch_bounds__(256) void k_remap(const int* __restrict__ src,
        const int* __restrict__ dst, const int* __restrict__ map,
        int* __restrict__ ns, int* __restrict__ nd) {
    const int e = blockIdx.x * 256 + threadIdx.x;
    const int a = map[src[e]];
    const int b = map[dst[e]];
    const bool ok = (a >= 0) && (b >= 0);
    ns[e] = ok ? a : -1;
    nd[e] = ok ? b : -1;
}

// ---------- x2 readout ----------
__global__ __launch_bounds__(256) void k_x2(const float* __restrict__ H2,
        const int* __restrict__ perm, const float* __restrict__ vals,
        float* __restrict__ X2) {
    const int g = blockIdx.x, c = threadIdx.x;
    float mx = -FLT_MAX, sm = 0.f;
    for (int i = 0; i < K2; ++i) {
        const int idx = g * K2 + i;
        const int srow = perm[idx];
        const float v = H2[(size_t)srow * HID + c] * vals[idx];
        mx = fmaxf(mx, v);
        sm += v;
    }
    X2[g * 512 + c] = mx;
    X2[g * 512 + 256 + c] = sm * (1.f / K2);
}

// ---------- final linear: out = (x1+x2) @ Wl + bl ----------
__global__ __launch_bounds__(256) void k_final(const float* __restrict__ X1,
        const float* __restrict__ X2, const float* __restrict__ Wl,
        const float* __restrict__ bl, float* __restrict__ out) {
    const int g = blockIdx.x, c = threadIdx.x;
    float acc = bl[c];
    for (int k = 0; k < 512; ++k) {
        const float xv = X1[g * 512 + k] + X2[g * 512 + k];
        acc = fmaf(xv, Wl[k * HID + c], acc);
    }
    out[g * HID + c] = acc;
}

extern "C" void kernel_launch(void* const* d_in, const int* in_sizes, int n_in,
                              void* d_out, int out_size, void* d_ws, size_t ws_size,
                              hipStream_t stream) {
    (void)in_sizes; (void)n_in; (void)out_size; (void)ws_size;
    const float* x       = (const float*)d_in[0];
    const int*   src     = (const int*)  d_in[1];
    const int*   dst     = (const int*)  d_in[2];
    const float* W_rel1  = (const float*)d_in[3];
    const float* b_rel1  = (const float*)d_in[4];
    const float* W_root1 = (const float*)d_in[5];
    const float* g1      = (const float*)d_in[6];
    const float* bt1     = (const float*)d_in[7];
    const float* p1      = (const float*)d_in[8];
    const float* g2      = (const float*)d_in[9];
    const float* bt2     = (const float*)d_in[10];
    const float* W_rel2  = (const float*)d_in[11];
    const float* b_rel2  = (const float*)d_in[12];
    const float* W_root2 = (const float*)d_in[13];
    const float* p2      = (const float*)d_in[14];
    const float* Wl      = (const float*)d_in[15];
    const float* bl      = (const float*)d_in[16];
    float* out = (float*)d_out;

    char* w = (char*)d_ws;
    size_t off = 0;
    auto alloc = [&](size_t bytes) -> void* {
        void* p = w + off;
        off += (bytes + 255) & ~(size_t)255;
        return p;
    };
    float* A1     = (float*)alloc((size_t)NN0 * 256 * 4);   // [agg1 | x], later h2
    float* HG     = (float*)alloc((size_t)NN0 * 256 * 4);   // gelu(conv1), later A2
    float* H1P    = (float*)alloc((size_t)NN1 * 256 * 4);
    int*   NS     = (int*)  alloc((size_t)NE * 4);
    int*   ND     = (int*)  alloc((size_t)NE * 4);
    float* SCORES = (float*)alloc((size_t)NN0 * 4);         // reused for pool2
    int*   PERM1  = (int*)  alloc((size_t)NN1 * 4);
    float* VALS1  = (float*)alloc((size_t)NN1 * 4);
    int*   MAP1   = (int*)  alloc((size_t)NN0 * 4);
    int*   PERM2  = (int*)  alloc((size_t)NN2 * 4);
    float* VALS2  = (float*)alloc((size_t)NN2 * 4);
    float* STATS1 = (float*)alloc(512 * 4);
    float* STATS2 = (float*)alloc(512 * 4);
    float* SCALE1 = (float*)alloc(256 * 4);
    float* SHIFT1 = (float*)alloc(256 * 4);
    float* Q1     = (float*)alloc(256 * 4);
    float* R1     = (float*)alloc(256);
    float* SCALE2 = (float*)alloc(256 * 4);
    float* SHIFT2 = (float*)alloc(256 * 4);
    float* Q2     = (float*)alloc(256 * 4);
    float* W1C    = (float*)alloc((size_t)256 * 256 * 4);
    float* W2C    = (float*)alloc((size_t)512 * 256 * 4);
    float* X1     = (float*)alloc((size_t)GG * 512 * 4);
    float* X2     = (float*)alloc((size_t)GG * 512 * 4);
    float* A2 = HG;   // alias: h_gelu dead before A2 is written
    float* H2 = A1;   // alias: A1 dead before h2 is written

    hipMemsetAsync(STATS1, 0, 512 * sizeof(float), stream);
    hipMemsetAsync(STATS2, 0, 512 * sizeof(float), stream);
    hipMemsetAsync(MAP1, 0xFF, (size_t)NN0 * sizeof(int), stream);

    k_w1cat<<<256, 256, 0, stream>>>(W_rel1, W_root1, W1C);
    k_w2cat<<<512, 256, 0, stream>>>(W_rel2, W_root2, W2C);
    k_q2norm<<<1, 256, 0, stream>>>(p2, Q2);
    k_copy_x<<<2048, 256, 0, stream>>>(x, A1);
    k_agg1<<<1024, 256, 0, stream>>>(x, src, dst, A1);
    k_gemm128<1><<<dim3(512, 2), 256, 0, stream>>>(A1, W1C, b_rel1, HG, STATS1, NN0, 256, 256);
    k_finalize1<<<1, 256, 0, stream>>>(STATS1, g1, bt1, p1, SCALE1, SHIFT1, Q1, R1);
    k_score<<<NN0 / 4, 256, 0, stream>>>(HG, Q1, R1, SCORES);
    k_topk<NPG, K1, 512><<<GG, 512, 0, stream>>>(SCORES, PERM1, VALS1, MAP1);
    k_pool1<<<GG, 256, 0, stream>>>(HG, PERM1, VALS1, SCALE1, SHIFT1, H1P, X1, STATS2);
    k_finalize2<<<1, 256, 0, stream>>>(STATS2, g2, bt2, SCALE2, SHIFT2);
    k_h2in<<<2048, 256, 0, stream>>>(H1P, SCALE2, SHIFT2, A2);
    k_remap<<<NE / 256, 256, 0, stream>>>(src, dst, MAP1, NS, ND);
    k_agg2<<<1024, 256, 0, stream>>>(A2, NS, ND, A2);
    k_gemm128<0><<<dim3(256, 2), 256, 0, stream>>>(A2, W2C, b_rel2, H2, nullptr, NN1, 512, 256);
    k_score<<<NN1 / 4, 256, 0, stream>>>(H2, Q2, nullptr, SCORES);
    k_topk<K1, K2, 256><<<GG, 256, 0, stream>>>(SCORES, PERM2, VALS2, nullptr);
    k_x2<<<GG, 256, 0, stream>>>(H2, PERM2, VALS2, X2);
    k_final<<<GG, 256, 0, stream>>>(X1, X2, Wl, bl, out);
}